// Round 16
// baseline (626.586 us; speedup 1.0000x reference)
//
#include <hip/hip_runtime.h>
#include <hip/hip_fp16.h>
#include <cstdint>
#include <cstddef>

constexpr int NN  = 100000;
constexpr int EE  = 1600000;
constexpr int HID = 128;
constexpr int BUK = 256;                      // nodes per bucket (local id fits 8 bits)
constexpr int NBUK = (NN + BUK - 1) / BUK;    // 391 buckets
constexpr int BLKE = 2048;                    // edges per block in bucket passes
constexpr int NBE  = (EE + BLKE - 1) / BLKE;  // 782 edge blocks
constexpr int MH   = NBUK * NBE;              // 305762 flattened hist entries
constexpr int MH2  = 2 * MH;                  // concatenated dst|src histograms
constexpr int NSC  = (MH2 + 2047) / 2048;     // 299 scan chunks (<=512 for scan_top)

typedef float f32x4_t __attribute__((ext_vector_type(4)));
typedef short bf16x8_t __attribute__((ext_vector_type(8)));

static __device__ __forceinline__ short f2bf(float f) {
    union { float f; unsigned u; } x; x.f = f;
    unsigned r = x.u + 0x7FFF + ((x.u >> 16) & 1);   // RN-even
    return (short)(r >> 16);
}
static __device__ __forceinline__ float bf2f(short b) {
    union { unsigned u; float f; } x; x.u = ((unsigned)(unsigned short)b) << 16;
    return x.f;
}

// ---------------------------------------------------------------- pass 1: per-block bucket histograms, both sides (LDS atomics only)
__global__ __launch_bounds__(256) void bh_both_k(const int* __restrict__ src, const int* __restrict__ dst,
                                                 int* __restrict__ bh2) {
    __shared__ int hd[NBUK], hs[NBUK];
    int blk = blockIdx.x, t = threadIdx.x;
    for (int i = t; i < NBUK; i += 256) { hd[i] = 0; hs[i] = 0; }
    __syncthreads();
    int e0 = blk * BLKE, e1 = min(e0 + BLKE, EE);
    for (int e = e0 + t; e < e1; e += 256) {
        atomicAdd(&hd[dst[e] >> 8], 1);
        atomicAdd(&hs[src[e] >> 8], 1);
    }
    __syncthreads();
    for (int i = t; i < NBUK; i += 256) {
        bh2[i * NBE + blk]      = hd[i];
        bh2[MH + i * NBE + blk] = hs[i];
    }
}

// ---------------------------------------------------------------- 3-level exclusive scan over 2*MH (2048 elems/block)
__global__ __launch_bounds__(256) void scan_sum_k(const int* __restrict__ in, int* __restrict__ bsum, int n) {
    __shared__ int sc[256];
    int b = blockIdx.x, t = threadIdx.x;
    int base = b * 2048 + t * 8;
    int s = 0;
#pragma unroll
    for (int j = 0; j < 8; j++) { int idx = base + j; s += (idx < n) ? in[idx] : 0; }
    sc[t] = s; __syncthreads();
    for (int off = 128; off > 0; off >>= 1) {
        if (t < off) sc[t] += sc[t + off];
        __syncthreads();
    }
    if (t == 0) bsum[b] = sc[0];
}

__global__ __launch_bounds__(512) void scan_top_k(const int* __restrict__ bsum, int* __restrict__ boff, int nb) {
    __shared__ int sc[512];
    int t = threadIdx.x;
    int v = (t < nb) ? bsum[t] : 0;
    sc[t] = v; __syncthreads();
    for (int off = 1; off < 512; off <<= 1) {
        int u = (t >= off) ? sc[t - off] : 0;
        __syncthreads();
        sc[t] += u;
        __syncthreads();
    }
    if (t < nb) boff[t] = sc[t] - v;
}

__global__ __launch_bounds__(256) void scan_chunk_k(const int* __restrict__ in, const int* __restrict__ boff,
                                                    int* __restrict__ out, int n) {
    __shared__ int sc[256];
    int b = blockIdx.x, t = threadIdx.x;
    int base = b * 2048 + t * 8;
    int c[8];
    int s = 0;
#pragma unroll
    for (int j = 0; j < 8; j++) { int idx = base + j; c[j] = (idx < n) ? in[idx] : 0; s += c[j]; }
    sc[t] = s; __syncthreads();
    for (int off = 1; off < 256; off <<= 1) {
        int v = (t >= off) ? sc[t - off] : 0;
        __syncthreads();
        sc[t] += v;
        __syncthreads();
    }
    int excl = sc[t] - s + boff[b];
#pragma unroll
    for (int j = 0; j < 8; j++) {
        int idx = base + j;
        if (idx < n) out[idx] = excl;
        excl += c[j];
    }
}

// ---------------------------------------------------------------- pass 2: scatter into bucket order (LDS cursors)
__global__ __launch_bounds__(256) void scatter_both_k(const int* __restrict__ src, const int* __restrict__ dst,
                                                      const int* __restrict__ off2,
                                                      unsigned* __restrict__ pairs, unsigned char* __restrict__ sbyte) {
    __shared__ int cd[NBUK], cs[NBUK];
    int blk = blockIdx.x, t = threadIdx.x;
    for (int i = t; i < NBUK; i += 256) {
        cd[i] = off2[i * NBE + blk];
        cs[i] = off2[MH + i * NBE + blk] - EE;
    }
    __syncthreads();
    int e0 = blk * BLKE, e1 = min(e0 + BLKE, EE);
    for (int e = e0 + t; e < e1; e += 256) {
        int d = dst[e], s = src[e];
        int pd = atomicAdd(&cd[d >> 8], 1);
        pairs[pd] = ((unsigned)(d & 255) << 17) | (unsigned)s;
        int ps = atomicAdd(&cs[s >> 8], 1);
        sbyte[ps] = (unsigned char)(s & 255);
    }
}

// ---------------------------------------------------------------- per-bucket work, fused
__global__ __launch_bounds__(512) void bucket_csr_ocnt_k(
    const unsigned* __restrict__ pairs, const unsigned char* __restrict__ sbyte,
    const int* __restrict__ off2,
    int* __restrict__ rowptr, int* __restrict__ col,
    float* __restrict__ inorm, float* __restrict__ onorm) {
    __shared__ int hist[BUK];
    __shared__ int excl[BUK];
    __shared__ int psum[BUK];
    int t = threadIdx.x;

    if (blockIdx.x >= NBUK) {            // -------- out-degree counting
        int b = blockIdx.x - NBUK;
        int base = off2[MH + b * NBE] - EE;
        int endv = (b == NBUK - 1) ? EE : off2[MH + (b + 1) * NBE] - EE;
        if (t < BUK) hist[t] = 0;
        __syncthreads();
        for (int i = base + t; i < endv; i += 512) atomicAdd(&hist[sbyte[i]], 1);
        __syncthreads();
        if (t < BUK) {
            int node = b * BUK + t;
            if (node < NN) {
                int c = hist[t]; if (c < 1) c = 1;
                onorm[node] = rsqrtf((float)c);
            }
        }
        return;
    }

    int b = blockIdx.x;
    int base = off2[b * NBE];
    int endv = (b == NBUK - 1) ? EE : off2[(b + 1) * NBE];
    if (t < BUK) hist[t] = 0;
    __syncthreads();
    for (int i = base + t; i < endv; i += 512) atomicAdd(&hist[pairs[i] >> 17], 1);
    __syncthreads();
    int ps = 0;
    if (t < BUK) { ps = hist[t]; psum[t] = ps; }
    __syncthreads();
    for (int off = 1; off < BUK; off <<= 1) {
        int u = 0;
        if (t < BUK && t >= off) u = psum[t - off];
        __syncthreads();
        if (t < BUK) psum[t] += u;
        __syncthreads();
    }
    if (t < BUK) {
        int pex = psum[t] - ps;
        excl[t] = pex;
        int node = b * BUK + t;
        if (node < NN) {
            rowptr[node] = base + pex;
            int c = ps; if (c < 1) c = 1;
            inorm[node] = rsqrtf((float)c);
        }
    }
    if (b == NBUK - 1 && t == 0) rowptr[NN] = EE;
    __syncthreads();
    for (int i = base + t; i < endv; i += 512) {
        unsigned p = pairs[i];
        int pos = base + atomicAdd(&excl[p >> 17], 1);
        col[pos] = (int)(p & 0x1FFFFu);
    }
}

// ---------------------------------------------------------------- W12 = W1 @ W2 ; b12 = b1 @ W2 + b2; block 65: Wg2 split planes
__global__ __launch_bounds__(256) void w12_k(const float* __restrict__ W1, const float* __restrict__ W2,
                                             const float* __restrict__ b1, const float* __restrict__ b2,
                                             const float* __restrict__ Wg,
                                             float* __restrict__ W12, float* __restrict__ b12,
                                             short* __restrict__ wsp) {
    int t = threadIdx.x;
    if (blockIdx.x == 65) {
        // stage Wg2 to global split planes, sidx layout (R13 stage_w verbatim, NT=8)
        const float* W = Wg + 2 * 128 * 128;
        short* Bh = wsp;
        short* Bl = wsp + 16384;
        for (int j = 0; j < 16; j++) {
            int fi = (j * 256 + t) * 4;
            int k = fi >> 7, n0 = fi & 127;
            float4 wv = *(const float4*)(W + fi);
            float wa[4] = {wv.x, wv.y, wv.z, wv.w};
#pragma unroll
            for (int cc = 0; cc < 4; cc++) {
                int g = n0 + cc;
                int q2 = g >> 2;
                int ntc = q2 & 7;
                int c = ((q2 >> 3) << 2) | (g & 3);
                int kblk = k >> 5, ksub = k & 31;
                int lane_ = ((ksub >> 3) << 4) | c;
                int sidx = ((ntc * 4 + kblk) * 64 + lane_) * 8 + (ksub & 7);
                short hi = f2bf(wa[cc]);
                Bh[sidx] = hi; Bl[sidx] = f2bf(wa[cc] - bf2f(hi));
            }
        }
        return;
    }
    if (blockIdx.x == 64) {
        int j = t;
        if (j < 128) {
            float acc = b2[j];
            for (int k = 0; k < 128; k++) acc = fmaf(b1[k], W2[k * 128 + j], acc);
            b12[j] = acc;
        }
        return;
    }
    int idx = blockIdx.x * 256 + t;   // 0..16383
    int i = idx >> 7, j = idx & 127;
    float a0 = 0.f, a1 = 0.f, a2 = 0.f, a3 = 0.f;
    for (int k = 0; k < 128; k += 4) {
        a0 = fmaf(W1[i * 128 + k],     W2[(k)     * 128 + j], a0);
        a1 = fmaf(W1[i * 128 + k + 1], W2[(k + 1) * 128 + j], a1);
        a2 = fmaf(W1[i * 128 + k + 2], W2[(k + 2) * 128 + j], a2);
        a3 = fmaf(W1[i * 128 + k + 3], W2[(k + 3) * 128 + j], a3);
    }
    W12[idx] = (a0 + a1) + (a2 + a3);
}

// ---------------------------------------------------------------- aggregation (fp16 gather, fp32 acc, split-bf16 out) — R10 verbatim
__global__ __launch_bounds__(256) void agg_k(const float4* __restrict__ h16, const int* __restrict__ rowptr,
                                             const int* __restrict__ col, const float* __restrict__ inorm,
                                             short* __restrict__ h0h, short* __restrict__ h0l) {
    int w = (int)((blockIdx.x * 256 + threadIdx.x) >> 6);
    if (w >= NN) return;
    int lane = threadIdx.x & 63;
    int q   = lane >> 4;
    int l16 = lane & 15;
    int beg = rowptr[w], end = rowptr[w + 1];
    float acc[8];
#pragma unroll
    for (int j = 0; j < 8; j++) acc[j] = 0.f;

    union HU { float4 f4; __half2 h2[4]; };
    int i = beg + q;
    for (; i + 12 < end; i += 16) {        // per quarter: edges i, i+4, i+8, i+12
        int s0 = col[i], s1 = col[i + 4], s2 = col[i + 8], s3 = col[i + 12];
        HU u0, u1, u2, u3;
        u0.f4 = h16[(size_t)s0 * 16 + l16];
        u1.f4 = h16[(size_t)s1 * 16 + l16];
        u2.f4 = h16[(size_t)s2 * 16 + l16];
        u3.f4 = h16[(size_t)s3 * 16 + l16];
#pragma unroll
        for (int p = 0; p < 4; p++) {
            float2 a = __half22float2(u0.h2[p]);
            float2 b = __half22float2(u1.h2[p]);
            float2 c = __half22float2(u2.h2[p]);
            float2 d = __half22float2(u3.h2[p]);
            acc[2 * p]     += (a.x + b.x) + (c.x + d.x);
            acc[2 * p + 1] += (a.y + b.y) + (c.y + d.y);
        }
    }
    for (; i < end; i += 4) {
        int s = col[i];
        HU u; u.f4 = h16[(size_t)s * 16 + l16];
#pragma unroll
        for (int p = 0; p < 4; p++) {
            float2 a = __half22float2(u.h2[p]);
            acc[2 * p]     += a.x;
            acc[2 * p + 1] += a.y;
        }
    }
#pragma unroll
    for (int mm = 16; mm <= 32; mm <<= 1)
#pragma unroll
        for (int j = 0; j < 8; j++) acc[j] += __shfl_xor(acc[j], mm);
    if (q == 0) {
        float s = inorm[w];
        bf16x8_t hv, lv;
#pragma unroll
        for (int j = 0; j < 8; j++) {
            float v = acc[j] * s;
            short hi = f2bf(v);
            hv[j] = hi;
            lv[j] = f2bf(v - bf2f(hi));
        }
        *(bf16x8_t*)&h0h[(size_t)w * 128 + l16 * 8] = hv;
        *(bf16x8_t*)&h0l[(size_t)w * 128 + l16 * 8] = lv;
    }
}

// ---------------------------------------------------------------- split-bf16 MFMA GEMM, 2 tiles/iteration (R16)
// R13 refuted occupancy as the GEMM bottleneck; remaining arithmetic: 64
// ds_read_b128 per tile feed only 24 MFMA (~770 vs ~120 cyc) at a fixed 2
// waves/SIMD (LDS cap). Fix: process TWO 16-row tiles per iteration so each
// (bh, bl) LDS pair feeds 6 MFMA — weight reads per output row halved.
// __launch_bounds__(256,2) pins VGPR<=256 = 2 waves/SIMD (unchanged by
// construction). All users are OUTHALF+OUTSCALE, ncols=128, nrows%32==0.
// Weight staging, fragment addressing, Tr transpose store: R15 verbatim.
template <bool RELU, bool INSPLIT>
__global__ __launch_bounds__(256, 2) void mfma_gemm2_k(
    const void* __restrict__ in, const short* __restrict__ inl,
    const float* __restrict__ W, const float* __restrict__ bias,
    __half* __restrict__ outp, const float* __restrict__ outscale,
    int nst) {

    __shared__ short Bh[8 * 2048];   // [ntc][kblk(4)][lane(64)][j(8)]
    __shared__ short Bl[8 * 2048];
    __shared__ __half Tr[4 * 16 * 128];   // per-wave 16x128 transpose tile

    const int t = threadIdx.x;

    for (int j = 0; j < 16; j++) {
        int fi = (j * 256 + t) * 4;
        int k = fi >> 7, n0 = fi & 127;
        float4 wv = *(const float4*)(W + fi);
        float wa[4] = {wv.x, wv.y, wv.z, wv.w};
#pragma unroll
        for (int cc = 0; cc < 4; cc++) {
            int g = n0 + cc;
            int q2 = g >> 2;
            int ntc = q2 & 7;
            int c = ((q2 >> 3) << 2) | (g & 3);
            int kblk = k >> 5, ksub = k & 31;
            int lane_ = ((ksub >> 3) << 4) | c;
            int sidx = ((ntc * 4 + kblk) * 64 + lane_) * 8 + (ksub & 7);
            short hi = f2bf(wa[cc]);
            Bh[sidx] = hi; Bl[sidx] = f2bf(wa[cc] - bf2f(hi));
        }
    }
    __syncthreads();   // Bh/Bl read-only below

    const int wave = t >> 6;
    const int lane = t & 63;
    const int m    = lane & 15;
    const int kq   = lane >> 4;
    const int cbase = kq * 32;

    float bstat[32];
#pragma unroll
    for (int i = 0; i < 32; i++) bstat[i] = bias[cbase + i];

    const int wstride = gridDim.x * 4;
    for (int st = blockIdx.x * 4 + wave; st < nst; st += wstride) {
        const int row0 = st * 32 + m;        // tile0 = 2*st
        const int row1 = row0 + 16;          // tile1 = 2*st+1 (always < NN: nst*32 == NN)

        bf16x8_t A0h[4], A0l[4], A1h[4], A1l[4];
        if constexpr (INSPLIT) {
            const short* ih0 = (const short*)in + (size_t)row0 * 128 + kq * 8;
            const short* il0 = inl + (size_t)row0 * 128 + kq * 8;
#pragma unroll
            for (int kb = 0; kb < 4; kb++) {
                A0h[kb] = *(const bf16x8_t*)(ih0 + kb * 32);
                A0l[kb] = *(const bf16x8_t*)(il0 + kb * 32);
                A1h[kb] = *(const bf16x8_t*)(ih0 + 2048 + kb * 32);   // +16 rows
                A1l[kb] = *(const bf16x8_t*)(il0 + 2048 + kb * 32);
            }
        } else {
#pragma unroll
            for (int kb = 0; kb < 4; kb++) {
                const float* ap0 = (const float*)in + (size_t)row0 * 128 + kb * 32 + kq * 8;
                float4 p0 = *(const float4*)ap0;
                float4 p1 = *(const float4*)(ap0 + 4);
                float4 p2 = *(const float4*)(ap0 + 2048);        // row1
                float4 p3 = *(const float4*)(ap0 + 2048 + 4);
                float a0v[8] = {p0.x, p0.y, p0.z, p0.w, p1.x, p1.y, p1.z, p1.w};
                float a1v[8] = {p2.x, p2.y, p2.z, p2.w, p3.x, p3.y, p3.z, p3.w};
#pragma unroll
                for (int j = 0; j < 8; j++) {
                    short h0_ = f2bf(a0v[j]);
                    A0h[kb][j] = h0_;
                    A0l[kb][j] = f2bf(a0v[j] - bf2f(h0_));
                    short h1_ = f2bf(a1v[j]);
                    A1h[kb][j] = h1_;
                    A1l[kb][j] = f2bf(a1v[j] - bf2f(h1_));
                }
            }
        }

        const float osc0 = outscale[row0];
        const float osc1 = outscale[row1];

        float ov0[32] __attribute__((aligned(16)));
        float ov1[32] __attribute__((aligned(16)));
#pragma unroll
        for (int nt = 0; nt < 8; nt++) {
            f32x4_t a0 = {0.f, 0.f, 0.f, 0.f};
            f32x4_t a1 = {0.f, 0.f, 0.f, 0.f};
#pragma unroll
            for (int kb = 0; kb < 4; kb++) {
                const bf16x8_t bh = *(const bf16x8_t*)&Bh[((nt * 4 + kb) * 64 + lane) * 8];
                const bf16x8_t bl = *(const bf16x8_t*)&Bl[((nt * 4 + kb) * 64 + lane) * 8];
                a0 = __builtin_amdgcn_mfma_f32_16x16x32_bf16(bh, A0h[kb], a0, 0, 0, 0);
                a0 = __builtin_amdgcn_mfma_f32_16x16x32_bf16(bh, A0l[kb], a0, 0, 0, 0);
                a0 = __builtin_amdgcn_mfma_f32_16x16x32_bf16(bl, A0h[kb], a0, 0, 0, 0);
                a1 = __builtin_amdgcn_mfma_f32_16x16x32_bf16(bh, A1h[kb], a1, 0, 0, 0);
                a1 = __builtin_amdgcn_mfma_f32_16x16x32_bf16(bh, A1l[kb], a1, 0, 0, 0);
                a1 = __builtin_amdgcn_mfma_f32_16x16x32_bf16(bl, A1h[kb], a1, 0, 0, 0);
            }
#pragma unroll
            for (int r = 0; r < 4; r++) {
                float v0 = a0[r] + bstat[nt * 4 + r];
                float v1 = a1[r] + bstat[nt * 4 + r];
                if (RELU) { v0 = fmaxf(v0, 0.f); v1 = fmaxf(v1, 0.f); }
                ov0[nt * 4 + r] = v0 * osc0;
                ov1[nt * 4 + r] = v1 * osc1;
            }
        }

        // Tr transpose store, tile0 then tile1 (same-wave lgkmcnt ordering; R10 proven)
        __half* tw = &Tr[wave * 2048];
#pragma unroll
        for (int p = 0; p < 4; p++) {
            union { __half h[8]; float4 f4; } U;
#pragma unroll
            for (int j = 0; j < 8; j++) U.h[j] = __float2half_rn(ov0[p * 8 + j]);
            int bo = (cbase * 2 + p * 16) ^ ((m & 7) << 4);
            *(float4*)((char*)(tw + m * 128) + bo) = U.f4;
        }
#pragma unroll
        for (int s2 = 0; s2 < 4; s2++) {
            int r = s2 * 4 + (lane >> 4);
            int bo = ((lane & 15) * 16) ^ ((r & 7) << 4);
            float4 v = *(const float4*)((char*)(tw + r * 128) + bo);
            *(float4*)(outp + (size_t)(st * 32 + r) * 128 + (lane & 15) * 8) = v;
        }
#pragma unroll
        for (int p = 0; p < 4; p++) {
            union { __half h[8]; float4 f4; } U;
#pragma unroll
            for (int j = 0; j < 8; j++) U.h[j] = __float2half_rn(ov1[p * 8 + j]);
            int bo = (cbase * 2 + p * 16) ^ ((m & 7) << 4);
            *(float4*)((char*)(tw + m * 128) + bo) = U.f4;
        }
#pragma unroll
        for (int s2 = 0; s2 < 4; s2++) {
            int r = s2 * 4 + (lane >> 4);
            int bo = ((lane & 15) * 16) ^ ((r & 7) << 4);
            float4 v = *(const float4*)((char*)(tw + r * 128) + bo);
            *(float4*)(outp + (size_t)(st * 32 + 16 + r) * 128 + (lane & 15) * 8) = v;
        }
    }
}

// ---------------------------------------------------------------- FUSED last conv + classifier (R15 verbatim)
__global__ __launch_bounds__(256) void conv_cls_k(
    const short* __restrict__ inh, const short* __restrict__ inl,
    const short* __restrict__ gBh, const short* __restrict__ gBl,
    const float* __restrict__ bg2,
    const float* __restrict__ Wc, const float* __restrict__ bc,
    float* __restrict__ out, int ntiles) {

    __shared__ short WcH[3 * 2048];          // 12KB
    __shared__ short WcL[3 * 2048];          // 12KB
    __shared__ short Lh[4][16][136];         // 17.4KB bounce hi (row pad: 2-way banks)
    __shared__ short Ll[4][16][136];         // 17.4KB bounce lo

    const int t = threadIdx.x;

    // Wc staging (cls_gemm NT=3 verbatim)
    for (int idx = t; idx < 128 * 64; idx += 256) {
        int k = idx >> 6, g = idx & 63;
        if (g < 48) {
            float w = (g < 40) ? Wc[k * 40 + g] : 0.f;
            int q2 = g >> 2;
            int ntc = q2 % 3;
            int c = (q2 / 3) * 4 + (g & 3);
            int kblk = k >> 5, ksub = k & 31;
            int lane_ = ((ksub >> 3) << 4) | c;
            int sidx = ((ntc * 4 + kblk) * 64 + lane_) * 8 + (ksub & 7);
            short hi = f2bf(w);
            WcH[sidx] = hi; WcL[sidx] = f2bf(w - bf2f(hi));
        }
    }
    __syncthreads();

    const int wave = t >> 6;
    const int lane = t & 63;
    const int m    = lane & 15;
    const int kq   = lane >> 4;
    const int cbase = kq * 32;      // conv output cols (NT=8 permutation)
    const int cbc   = kq * 12;      // classifier output cols (NT=3 permutation)

    float bstat[32];
#pragma unroll
    for (int i = 0; i < 32; i++) bstat[i] = bg2[cbase + i];
    float bstatC[12];
#pragma unroll
    for (int i = 0; i < 12; i++) {
        int g = cbc + i;
        bstatC[i] = (g < 40) ? bc[g] : 0.f;
    }

    const int wstride = gridDim.x * 4;
    for (int tile = blockIdx.x * 4 + wave; tile < ntiles; tile += wstride) {
        const int row = tile * 16 + m;          // always < NN (ntiles*16 == NN)

        // ---- conv A-fragments (INSPLIT, R10 verbatim)
        bf16x8_t Ah[4], Al[4];
        {
            const short* ih = inh + (size_t)row * 128 + kq * 8;
            const short* il = inl + (size_t)row * 128 + kq * 8;
#pragma unroll
            for (int kb = 0; kb < 4; kb++) {
                Ah[kb] = *(const bf16x8_t*)(ih + kb * 32);
                Al[kb] = *(const bf16x8_t*)(il + kb * 32);
            }
        }

        // ---- conv NT=8 with global weight planes (R13 gw verbatim)
        float ov[32] __attribute__((aligned(16)));
#pragma unroll
        for (int nt = 0; nt < 8; nt++) {
            f32x4_t acc = {0.f, 0.f, 0.f, 0.f};
#pragma unroll
            for (int kb = 0; kb < 4; kb++) {
                const bf16x8_t bh = *(const bf16x8_t*)&gBh[((nt * 4 + kb) * 64 + lane) * 8];
                const bf16x8_t bl = *(const bf16x8_t*)&gBl[((nt * 4 + kb) * 64 + lane) * 8];
                acc = __builtin_amdgcn_mfma_f32_16x16x32_bf16(bh, Ah[kb], acc, 0, 0, 0);
                acc = __builtin_amdgcn_mfma_f32_16x16x32_bf16(bh, Al[kb], acc, 0, 0, 0);
                acc = __builtin_amdgcn_mfma_f32_16x16x32_bf16(bl, Ah[kb], acc, 0, 0, 0);
            }
#pragma unroll
            for (int r = 0; r < 4; r++) {
                float v = acc[r] + bstat[nt * 4 + r];
                ov[nt * 4 + r] = fmaxf(v, 0.f);       // ReLU, no outscale (last layer)
            }
        }

        // ---- bounce: split-bf16 into per-wave LDS tile (wave-synchronous)
#pragma unroll
        for (int p = 0; p < 4; p++) {
            bf16x8_t hv, lv;
#pragma unroll
            for (int j = 0; j < 8; j++) {
                float v = ov[p * 8 + j];
                short hi = f2bf(v);
                hv[j] = hi;
                lv[j] = f2bf(v - bf2f(hi));
            }
            *(bf16x8_t*)&Lh[wave][m][cbase + p * 8] = hv;
            *(bf16x8_t*)&Ll[wave][m][cbase + p * 8] = lv;
        }
        // same-wave ds_write -> ds_read ordering via lgkmcnt (Tr precedent)

        // ---- classifier (cls_gemm compute, fragments from bounce)
        float ovc[12] __attribute__((aligned(16)));
#pragma unroll
        for (int ntc = 0; ntc < 3; ntc++) {
            f32x4_t acc = {0.f, 0.f, 0.f, 0.f};
#pragma unroll
            for (int kb = 0; kb < 4; kb++) {
                const bf16x8_t wh = *(const bf16x8_t*)&WcH[((ntc * 4 + kb) * 64 + lane) * 8];
                const bf16x8_t wl = *(const bf16x8_t*)&WcL[((ntc * 4 + kb) * 64 + lane) * 8];
                const bf16x8_t fh = *(const bf16x8_t*)&Lh[wave][m][kb * 32 + kq * 8];
                const bf16x8_t fl = *(const bf16x8_t*)&Ll[wave][m][kb * 32 + kq * 8];
                acc = __builtin_amdgcn_mfma_f32_16x16x32_bf16(wh, fh, acc, 0, 0, 0);
                acc = __builtin_amdgcn_mfma_f32_16x16x32_bf16(wh, fl, acc, 0, 0, 0);
                acc = __builtin_amdgcn_mfma_f32_16x16x32_bf16(wl, fh, acc, 0, 0, 0);
            }
#pragma unroll
            for (int r = 0; r < 4; r++) ovc[ntc * 4 + r] = acc[r] + bstatC[ntc * 4 + r];
        }

        // ---- store (cls_gemm verbatim)
        float* p = out + (size_t)row * 40 + cbc;
#pragma unroll
        for (int j = 0; j < 3; j++) {
            if (cbc + j * 4 < 40) *(float4*)(p + j * 4) = ((const float4*)ovc)[j];
        }
    }
}

// ---------------------------------------------------------------- launch
extern "C" void kernel_launch(void* const* d_in, const int* in_sizes, int n_in,
                              void* d_out, int out_size, void* d_ws, size_t ws_size,
                              hipStream_t stream) {
    const float* x   = (const float*)d_in[0];
    const int*   src = (const int*)d_in[1];
    const int*   dst = (const int*)d_in[2];
    const float* W1  = (const float*)d_in[3];
    const float* b1  = (const float*)d_in[4];
    const float* W2  = (const float*)d_in[5];
    const float* b2  = (const float*)d_in[6];
    const float* Wg  = (const float*)d_in[7];   // [3][128][128]
    const float* bg  = (const float*)d_in[8];   // [3][128]
    const float* Wc  = (const float*)d_in[9];   // [128][40]
    const float* bc  = (const float*)d_in[10];  // [40]
    float* out = (float*)d_out;

    char* ws = (char*)d_ws;
    size_t off = 0;
    auto alloc = [&](size_t bytes) -> void* {
        void* p = ws + off;
        off += (bytes + 255) & ~(size_t)255;
        return p;
    };
    short*  h0h    = (short*)alloc((size_t)NN * HID * 2);    // agg out hi plane (bf16)
    short*  h0l    = (short*)alloc((size_t)NN * HID * 2);    // agg out lo plane (bf16)
    __half* h16    = (__half*)alloc((size_t)NN * HID * 2);   // agg in (fp16)
    float*  W12    = (float*)alloc(128 * 128 * 4);
    float*  b12    = (float*)alloc(128 * 4);
    short*  wsp    = (short*)alloc(2 * 16384 * 2);           // Wg2 global split planes (64KB)
    float*  onorm  = (float*)alloc((size_t)NN * 4);
    float*  inorm  = (float*)alloc((size_t)NN * 4);
    int*    rowptr = (int*)alloc((size_t)(NN + 1) * 4);
    int*    col    = (int*)alloc((size_t)EE * 4);
    int*    bh2    = (int*)alloc((size_t)MH2 * 4);
    int*    off2   = (int*)alloc((size_t)MH2 * 4);
    int*    bsum   = (int*)alloc((size_t)NSC * 4);
    int*    boff   = (int*)alloc((size_t)NSC * 4);
    // sort payloads alias h0h (consumed by bucket_csr_ocnt_k before agg writes)
    unsigned*      pairs = (unsigned*)h0h;                          // 6.4 MB
    unsigned char* sbyte = (unsigned char*)h0h + (size_t)EE * 4;    // 1.6 MB (within h0h)

    // ---- CSR build (no global atomics): single merged scan over dst|src
    bh_both_k<<<NBE, 256, 0, stream>>>(src, dst, bh2);
    scan_sum_k<<<NSC, 256, 0, stream>>>(bh2, bsum, MH2);
    scan_top_k<<<1, 512, 0, stream>>>(bsum, boff, NSC);
    scan_chunk_k<<<NSC, 256, 0, stream>>>(bh2, boff, off2, MH2);
    scatter_both_k<<<NBE, 256, 0, stream>>>(src, dst, off2, pairs, sbyte);
    bucket_csr_ocnt_k<<<2 * NBUK, 512, 0, stream>>>(pairs, sbyte, off2,
                                                    rowptr, col, inorm, onorm);

    // ---- weight fusion + Wg2 plane staging (blocks 0..63: W12; 64: b12; 65: Wg2 planes)
    w12_k<<<66, 256, 0, stream>>>(W1, W2, b1, b2, Wg, W12, b12, wsp);

    const int ntiles = NN / 16;          // 6250 (exact)
    const int nst    = NN / 32;          // 3125 supertiles (exact)
    const int g2grid = 391;              // 1564 waves x 2 supertiles = 3128 ~ nst

    // h16 = (x @ W12 + b12) * onorm           (fused feature1+feature2)
    mfma_gemm2_k<false, false><<<g2grid, 256, 0, stream>>>(
        x, nullptr, W12, b12, h16, onorm, nst);
    for (int l = 0; l < 3; l++) {
        // (h0h,h0l) = split( inorm * sum_{src} h16[src] )
        agg_k<<<(NN * 64 + 255) / 256, 256, 0, stream>>>(
            (const float4*)h16, rowptr, col, inorm, h0h, h0l);
        if (l < 2) {
            // h16 = relu(h0 @ Wg + bg) * onorm   (fp16 out, feeds agg)
            mfma_gemm2_k<true, true><<<g2grid, 256, 0, stream>>>(
                h0h, h0l, Wg + (size_t)l * 128 * 128, bg + (size_t)l * 128, h16, onorm, nst);
        } else {
            // out = relu(h0 @ Wg2 + bg2) @ Wc + bc   (fused last conv + classifier)
            conv_cls_k<<<512, 256, 0, stream>>>(
                h0h, h0l, wsp, wsp + 16384, bg + 2 * 128, Wc, bc, out, ntiles);
        }
    }
}